// Round 2
// baseline (812.171 us; speedup 1.0000x reference)
//
#include <hip/hip_runtime.h>

// GraphSAGE 3-layer: N=100000, E=3.2M, 128 -> 128 -> 128 -> 64.
// Round 8: 64B-granule XCD-pinned slabs via (channel-group x src-half) split.
//  - Round-7 lesson: gathers are L2 REQUEST-RATE bound (~188 G req/s); 16-ch
//    slices forced a 32B granule -> 2x requests for the same bytes -> slower.
//  - New decomposition: 4 channel-groups (32ch = 64B/edge) x 2 src-halves.
//    Slab = [N/2 src rows][32ch] = 3.2 MB -> resident in one XCD's 4MB L2.
//    slice = blockIdx%8 (c*2+s) pins each slab to one XCD.
//  - Edges sub-sorted by (dst, src_half): fine-sort key = (node<<1)|half,
//    rp2[2N+1]. Each slice walks only its half -> index traffic halves.
//  - Gathers emit PARTIAL SUMS (fp32-accum -> fp16); the two halves are
//    combined * invdeg[] in the GEMM A-operand load (GEMM is cheap).
//  - sorted_src loads + partial stores are NONTEMPORAL -> stop evicting slab.
//  - Row-major feature copies dropped: GEMM root operand reads slab layout
//    directly ([4][N][32]; fragment k=ch*32+q*8 -> slab[ch][row][q*8], 16B
//    contiguous). Layer 3: z in [2][N][32], 2ch-groups x 2 halves (slice
//    mirrored on 2 XCDs), 2 partials combined in final GEMM.

#define NN 100000
#define CHUNK 8192

typedef _Float16 half_t;
typedef __attribute__((ext_vector_type(4))) _Float16 half4v;
typedef __attribute__((ext_vector_type(8))) _Float16 half8v;
typedef __attribute__((ext_vector_type(4))) float float4v;

// ---- Pass A: coarse histogram (LDS-privatized) ----
__global__ __launch_bounds__(256) void coarse_hist_kernel(const int* __restrict__ dst,
                                                          int* __restrict__ ghist, int E) {
    __shared__ int h[1024];
    int tid = threadIdx.x;
    for (int i = tid; i < 1024; i += 256) h[i] = 0;
    __syncthreads();
    int base = blockIdx.x * CHUNK;
    int nE = min(CHUNK, E - base);
    for (int i = tid; i < nE; i += 256) atomicAdd(&h[dst[base + i] >> 7], 1);
    __syncthreads();
    for (int i = tid; i < 1024; i += 256) {
        int v = h[i];
        if (v) atomicAdd(&ghist[i], v);
    }
}

// ---- Pass B: scan 1024 coarse bins ----
__global__ __launch_bounds__(1024) void coarse_scan_kernel(const int* __restrict__ ghist,
                                                           int* __restrict__ cptr,
                                                           int* __restrict__ cfill,
                                                           int* __restrict__ rp2,
                                                           int n, int E) {
    __shared__ int s[1024];
    int tid = threadIdx.x;
    s[tid] = ghist[tid];
    __syncthreads();
    for (int off = 1; off < 1024; off <<= 1) {
        int v = (tid >= off) ? s[tid - off] : 0;
        __syncthreads();
        s[tid] += v;
        __syncthreads();
    }
    int excl = (tid == 0) ? 0 : s[tid - 1];
    cptr[tid] = excl;
    cfill[tid] = excl;
    if (tid == 1023) {
        cptr[1024] = s[1023];
        rp2[2 * n] = E;
    }
}

// ---- Pass C: partition edges into coarse buckets (packed u32) ----
__global__ __launch_bounds__(256) void partition_kernel(const int* __restrict__ src,
                                                        const int* __restrict__ dst,
                                                        int* __restrict__ cfill,
                                                        unsigned int* __restrict__ coarse,
                                                        int E) {
    __shared__ int h[1024];
    __shared__ int off[1024];
    __shared__ int gbase[1024];
    __shared__ int ssum[256];
    __shared__ unsigned int stage[CHUNK];
    int tid = threadIdx.x;
    for (int i = tid; i < 1024; i += 256) h[i] = 0;
    __syncthreads();
    int base = blockIdx.x * CHUNK;
    int nE = min(CHUNK, E - base);
    for (int i = tid; i < nE; i += 256) atomicAdd(&h[dst[base + i] >> 7], 1);
    __syncthreads();
    int b0 = tid * 4;
    int sum = h[b0] + h[b0 + 1] + h[b0 + 2] + h[b0 + 3];
    ssum[tid] = sum;
    __syncthreads();
    for (int o = 1; o < 256; o <<= 1) {
        int v = (tid >= o) ? ssum[tid - o] : 0;
        __syncthreads();
        ssum[tid] += v;
        __syncthreads();
    }
    int run = (tid == 0) ? 0 : ssum[tid - 1];
#pragma unroll
    for (int j = 0; j < 4; j++) { off[b0 + j] = run; run += h[b0 + j]; }
    __syncthreads();
    for (int i = tid; i < nE; i += 256) {
        int d = dst[base + i];
        int s_ = src[base + i];
        int bin = d >> 7;
        int pos = atomicAdd(&off[bin], 1);
        stage[pos] = ((unsigned)(d & 127) << 17) | (unsigned)s_;
    }
    __syncthreads();
#pragma unroll
    for (int j = 0; j < 4; j++) {
        int b = b0 + j;
        if (h[b]) gbase[b] = atomicAdd(&cfill[b], h[b]);
    }
#pragma unroll
    for (int j = 0; j < 4; j++) {
        int b = b0 + j;
        int c = h[b];
        int lstart = off[b] - c;
        int gs = gbase[b];
        for (int k = 0; k < c; k++) coarse[gs + k] = stage[lstart + k];
    }
}

// ---- Pass D: fine sort by (node, src_half) within each coarse bucket ----
__global__ __launch_bounds__(256) void fine_sort_kernel(const unsigned int* __restrict__ coarse,
                                                        const int* __restrict__ cptr,
                                                        int* __restrict__ rp2,
                                                        int* __restrict__ sorted_src, int n) {
    __shared__ int fh[256];
    __shared__ int foff[256];
    int b = blockIdx.x;
    int beg = cptr[b], end = cptr[b + 1];
    int nb = end - beg;
    int tid = threadIdx.x;
    fh[tid] = 0;
    __syncthreads();
    for (int i = tid; i < nb; i += 256) {
        unsigned p = coarse[beg + i];
        int f = (int)((p >> 17) << 1) | ((p & 0x1FFFF) >= (NN / 2) ? 1 : 0);
        atomicAdd(&fh[f], 1);
    }
    __syncthreads();
    foff[tid] = fh[tid];
    __syncthreads();
    for (int o = 1; o < 256; o <<= 1) {
        int v = (tid >= o) ? foff[tid - o] : 0;
        __syncthreads();
        foff[tid] += v;
        __syncthreads();
    }
    if (b * 128 + (tid >> 1) < n) rp2[b * 256 + tid] = beg + foff[tid] - fh[tid];
    foff[tid] -= fh[tid];
    __syncthreads();
    for (int i = tid; i < nb; i += 256) {
        unsigned p = coarse[beg + i];
        int f = (int)((p >> 17) << 1) | ((p & 0x1FFFF) >= (NN / 2) ? 1 : 0);
        int pos = atomicAdd(&foff[f], 1);
        sorted_src[beg + pos] = (int)(p & 0x1FFFF);
    }
}

// ---- invdeg[v] = 1/deg(v) (0 if isolated) ----
__global__ void invdeg_kernel(const int* __restrict__ rp2, float* __restrict__ inv, int n) {
    int t = blockIdx.x * 256 + threadIdx.x;
    if (t < n) {
        int d = rp2[2 * t + 2] - rp2[2 * t];
        inv[t] = d > 0 ? 1.0f / (float)d : 0.0f;
    }
}

// ---- fp32 -> fp16 cast, writes group-major [4][N][32] ----
__global__ void cast_f2h(const float* __restrict__ in, half_t* __restrict__ out, int n4) {
    constexpr size_t SLAB32 = (size_t)NN * 32;
    int t = blockIdx.x * blockDim.x + threadIdx.x;
    if (t < n4) {
        float4 v = *(const float4*)(in + (size_t)t * 4);
        half4v r = {(half_t)v.x, (half_t)v.y, (half_t)v.z, (half_t)v.w};
        int e = t * 4;
        int node = e >> 7;
        int c = e & 127;
        *(half4v*)(out + (size_t)(c >> 5) * SLAB32 + (size_t)node * 32 + (c & 31)) = r;
    }
}

// ---- weight prep: fragment-contiguous fp16; all 6 weights in one launch ----
template <int C_IN, int C_OUT>
__device__ inline void prep_one(const float* __restrict__ W, half_t* __restrict__ B, int t) {
    constexpr int NCT = C_OUT / 16;
    if (t >= C_IN * C_OUT) return;
    int jj = t & 7;
    int kq = (t >> 3) & 3;
    int c = (t >> 5) & 15;
    int ct = (t >> 9) % NCT;
    int chunk = t / (512 * NCT);
    int k = chunk * 32 + kq * 8 + jj;
    int j = ct * 16 + c;
    B[t] = (half_t)W[(size_t)j * C_IN + k];
}

__global__ __launch_bounds__(256) void prep_all(
    const float* __restrict__ Wl1, const float* __restrict__ Wr1,
    const float* __restrict__ Wl2, const float* __restrict__ Wr2,
    const float* __restrict__ Wl3, const float* __restrict__ Wr3,
    half_t* Bl1, half_t* Br1, half_t* Bl2, half_t* Br2, half_t* Bl3, half_t* Br3) {
    int b = blockIdx.x;
    int tid = threadIdx.x;
    if (b < 256) {
        int sel = b >> 6;
        int t = (b & 63) * 256 + tid;
        const float* W = sel == 0 ? Wl1 : sel == 1 ? Wr1 : sel == 2 ? Wl2 : Wr2;
        half_t* B = sel == 0 ? Bl1 : sel == 1 ? Br1 : sel == 2 ? Bl2 : Br2;
        prep_one<128, 128>(W, B, t);
    } else {
        int idx = b - 256;
        int sel = idx >> 5;
        int t = (idx & 31) * 256 + tid;
        prep_one<128, 64>(sel == 0 ? Wl3 : Wr3, sel == 0 ? Bl3 : Br3, t);
    }
}

// ---- gather partial sums, 128ch: slice = (chgrp 0..3)*2 + (half 0..1) ----
// Per node: 8 lanes = 2 edge-slots x 4 col-lanes (16B each -> 64B/edge).
// Unroll x4 -> 4 x 16B in flight/lane. 32 nodes/block, grid = (N/32)*8.
__global__ __launch_bounds__(256) void gather_part128(
    const half_t* __restrict__ feat,   // [4][N][32]
    const int* __restrict__ rp2,
    const int* __restrict__ sorted_src,
    half_t* __restrict__ part0,        // [N][128] sums, half 0
    half_t* __restrict__ part1,        // [N][128] sums, half 1
    int n) {
    constexpr size_t SLAB32 = (size_t)NN * 32;
    int slice = blockIdx.x & 7;
    int cg = slice >> 1;
    int s = slice & 1;
    int tid = threadIdx.x;
    int node = (blockIdx.x >> 3) * 32 + (tid >> 3);
    if (node >= n) return;
    int slot = (tid >> 2) & 1;
    int col = tid & 3;
    const half_t* base = feat + (size_t)cg * SLAB32 + col * 8;
    int beg = rp2[2 * node + s];
    int end = rp2[2 * node + s + 1];
    float a0 = 0.f, a1 = 0.f, a2 = 0.f, a3 = 0.f, a4 = 0.f, a5 = 0.f, a6 = 0.f, a7 = 0.f;
    int j = beg + slot;
    for (; j + 6 < end; j += 8) {
        int s0 = __builtin_nontemporal_load(sorted_src + j);
        int s1 = __builtin_nontemporal_load(sorted_src + j + 2);
        int s2 = __builtin_nontemporal_load(sorted_src + j + 4);
        int s3 = __builtin_nontemporal_load(sorted_src + j + 6);
        half8v v0 = *(const half8v*)(base + (size_t)s0 * 32);
        half8v v1 = *(const half8v*)(base + (size_t)s1 * 32);
        half8v v2 = *(const half8v*)(base + (size_t)s2 * 32);
        half8v v3 = *(const half8v*)(base + (size_t)s3 * 32);
        a0 += ((float)v0[0] + (float)v1[0]) + ((float)v2[0] + (float)v3[0]);
        a1 += ((float)v0[1] + (float)v1[1]) + ((float)v2[1] + (float)v3[1]);
        a2 += ((float)v0[2] + (float)v1[2]) + ((float)v2[2] + (float)v3[2]);
        a3 += ((float)v0[3] + (float)v1[3]) + ((float)v2[3] + (float)v3[3]);
        a4 += ((float)v0[4] + (float)v1[4]) + ((float)v2[4] + (float)v3[4]);
        a5 += ((float)v0[5] + (float)v1[5]) + ((float)v2[5] + (float)v3[5]);
        a6 += ((float)v0[6] + (float)v1[6]) + ((float)v2[6] + (float)v3[6]);
        a7 += ((float)v0[7] + (float)v1[7]) + ((float)v2[7] + (float)v3[7]);
    }
    for (; j < end; j += 2) {
        int s0 = __builtin_nontemporal_load(sorted_src + j);
        half8v v0 = *(const half8v*)(base + (size_t)s0 * 32);
        a0 += (float)v0[0]; a1 += (float)v0[1]; a2 += (float)v0[2]; a3 += (float)v0[3];
        a4 += (float)v0[4]; a5 += (float)v0[5]; a6 += (float)v0[6]; a7 += (float)v0[7];
    }
    // reduce across the 2 edge slots (lane bit 2)
    a0 += __shfl_xor(a0, 4); a1 += __shfl_xor(a1, 4);
    a2 += __shfl_xor(a2, 4); a3 += __shfl_xor(a3, 4);
    a4 += __shfl_xor(a4, 4); a5 += __shfl_xor(a5, 4);
    a6 += __shfl_xor(a6, 4); a7 += __shfl_xor(a7, 4);
    if (slot == 0) {
        half8v r = {(half_t)a0, (half_t)a1, (half_t)a2, (half_t)a3,
                    (half_t)a4, (half_t)a5, (half_t)a6, (half_t)a7};
        half_t* pp = (s == 0 ? part0 : part1);
        __builtin_nontemporal_store(r, (half8v*)(pp + (size_t)node * 128 + cg * 32 + col * 8));
    }
}

// ---- gather partial sums, 64ch z: slice = (chhalf 0..1)*2 + (half 0..1),
//      mirrored on XCD pairs (x, x+4). grid = (N/32)*4. ----
__global__ __launch_bounds__(256) void gather_part64(
    const half_t* __restrict__ z,      // [2][N][32]
    const int* __restrict__ rp2,
    const int* __restrict__ sorted_src,
    half_t* __restrict__ part0,        // [N][64] sums, half 0
    half_t* __restrict__ part1,        // [N][64] sums, half 1
    int n) {
    constexpr size_t SLAB32 = (size_t)NN * 32;
    int slice = blockIdx.x & 3;
    int hg = slice >> 1;
    int s = slice & 1;
    int tid = threadIdx.x;
    int node = (blockIdx.x >> 2) * 32 + (tid >> 3);
    if (node >= n) return;
    int slot = (tid >> 2) & 1;
    int col = tid & 3;
    const half_t* base = z + (size_t)hg * SLAB32 + col * 8;
    int beg = rp2[2 * node + s];
    int end = rp2[2 * node + s + 1];
    float a0 = 0.f, a1 = 0.f, a2 = 0.f, a3 = 0.f, a4 = 0.f, a5 = 0.f, a6 = 0.f, a7 = 0.f;
    int j = beg + slot;
    for (; j + 6 < end; j += 8) {
        int s0 = __builtin_nontemporal_load(sorted_src + j);
        int s1 = __builtin_nontemporal_load(sorted_src + j + 2);
        int s2 = __builtin_nontemporal_load(sorted_src + j + 4);
        int s3 = __builtin_nontemporal_load(sorted_src + j + 6);
        half8v v0 = *(const half8v*)(base + (size_t)s0 * 32);
        half8v v1 = *(const half8v*)(base + (size_t)s1 * 32);
        half8v v2 = *(const half8v*)(base + (size_t)s2 * 32);
        half8v v3 = *(const half8v*)(base + (size_t)s3 * 32);
        a0 += ((float)v0[0] + (float)v1[0]) + ((float)v2[0] + (float)v3[0]);
        a1 += ((float)v0[1] + (float)v1[1]) + ((float)v2[1] + (float)v3[1]);
        a2 += ((float)v0[2] + (float)v1[2]) + ((float)v2[2] + (float)v3[2]);
        a3 += ((float)v0[3] + (float)v1[3]) + ((float)v2[3] + (float)v3[3]);
        a4 += ((float)v0[4] + (float)v1[4]) + ((float)v2[4] + (float)v3[4]);
        a5 += ((float)v0[5] + (float)v1[5]) + ((float)v2[5] + (float)v3[5]);
        a6 += ((float)v0[6] + (float)v1[6]) + ((float)v2[6] + (float)v3[6]);
        a7 += ((float)v0[7] + (float)v1[7]) + ((float)v2[7] + (float)v3[7]);
    }
    for (; j < end; j += 2) {
        int s0 = __builtin_nontemporal_load(sorted_src + j);
        half8v v0 = *(const half8v*)(base + (size_t)s0 * 32);
        a0 += (float)v0[0]; a1 += (float)v0[1]; a2 += (float)v0[2]; a3 += (float)v0[3];
        a4 += (float)v0[4]; a5 += (float)v0[5]; a6 += (float)v0[6]; a7 += (float)v0[7];
    }
    a0 += __shfl_xor(a0, 4); a1 += __shfl_xor(a1, 4);
    a2 += __shfl_xor(a2, 4); a3 += __shfl_xor(a3, 4);
    a4 += __shfl_xor(a4, 4); a5 += __shfl_xor(a5, 4);
    a6 += __shfl_xor(a6, 4); a7 += __shfl_xor(a7, 4);
    if (slot == 0) {
        half8v r = {(half_t)a0, (half_t)a1, (half_t)a2, (half_t)a3,
                    (half_t)a4, (half_t)a5, (half_t)a6, (half_t)a7};
        half_t* pp = (s == 0 ? part0 : part1);
        __builtin_nontemporal_store(r, (half8v*)(pp + (size_t)node * 64 + hg * 32 + col * 8));
    }
}

// ---- A-fragment load from group-major [4][N][32]: k = ch*32 + q*8 ----
__device__ inline half8v load_a32(const half_t* __restrict__ A, int rowc, int q, int ch) {
    constexpr size_t SLAB32 = (size_t)NN * 32;
    return *(const half8v*)(A + (size_t)ch * SLAB32 + (size_t)rowc * 32 + q * 8);
}

// ---- MFMA layers 1,2: out = relu( ((p0+p1)*invdeg)@Wl^T + bias + root@Wr^T )
//      root and out16 group-major [4][N][32]; partials row-major [N][128]. ----
__global__ __launch_bounds__(256) void mfma_layer128(
    const half_t* __restrict__ rootSl,
    const half_t* __restrict__ part0, const half_t* __restrict__ part1,
    const float* __restrict__ invdeg,
    const half_t* __restrict__ Bl, const half_t* __restrict__ Br,
    const float* __restrict__ bias, half_t* __restrict__ outSl, int n) {
    constexpr int NCT = 8;
    constexpr size_t SLAB32 = (size_t)NN * 32;
    int tid = threadIdx.x;
    int w = tid >> 6;
    int l = tid & 63;
    int c = l & 15;
    int q = l >> 4;
    int row = blockIdx.x * 64 + w * 16 + c;
    int rowc = min(row, n - 1);
    float iv = invdeg[rowc];

    float4v acc[NCT];
#pragma unroll
    for (int i = 0; i < NCT; i++) acc[i] = (float4v){0.f, 0.f, 0.f, 0.f};

    // mean stage: a = (p0+p1)*invdeg
    {
        const half_t* B = Bl + (size_t)(c * 4 + q) * 8;
#pragma unroll
        for (int ch = 0; ch < 4; ch++) {
            half8v p0 = *(const half8v*)(part0 + (size_t)rowc * 128 + ch * 32 + q * 8);
            half8v p1 = *(const half8v*)(part1 + (size_t)rowc * 128 + ch * 32 + q * 8);
            half8v a;
#pragma unroll
            for (int i = 0; i < 8; i++) a[i] = (half_t)(((float)p0[i] + (float)p1[i]) * iv);
            half8v b[NCT];
#pragma unroll
            for (int t2 = 0; t2 < NCT; t2++)
                b[t2] = *(const half8v*)(B + (size_t)ch * (NCT * 512) + t2 * 512);
#pragma unroll
            for (int t2 = 0; t2 < NCT; t2++)
                acc[t2] = __builtin_amdgcn_mfma_f32_16x16x32_f16(a, b[t2], acc[t2], 0, 0, 0);
        }
    }
    // root stage
    {
        const half_t* B = Br + (size_t)(c * 4 + q) * 8;
#pragma unroll
        for (int ch = 0; ch < 4; ch++) {
            half8v a = load_a32(rootSl, rowc, q, ch);
            half8v b[NCT];
#pragma unroll
            for (int t2 = 0; t2 < NCT; t2++)
                b[t2] = *(const half8v*)(B + (size_t)ch * (NCT * 512) + t2 * 512);
#pragma unroll
            for (int t2 = 0; t2 < NCT; t2++)
                acc[t2] = __builtin_amdgcn_mfma_f32_16x16x32_f16(a, b[t2], acc[t2], 0, 0, 0);
        }
    }

    int orow0 = blockIdx.x * 64 + w * 16 + q * 4;
#pragma unroll
    for (int t2 = 0; t2 < NCT; t2++) {
        int col = t2 * 16 + c;
        float bv = bias[col];
        size_t coff = (size_t)(col >> 5) * SLAB32 + (col & 31);
#pragma unroll
        for (int r = 0; r < 4; r++) {
            int nrow = orow0 + r;
            if (nrow < n)
                outSl[coff + (size_t)nrow * 32] = (half_t)fmaxf(acc[t2][r] + bv, 0.f);
        }
    }
}

// ---- MFMA layer-3 pre-transform: z = hh@Wl3^T, out group-major [2][N][32] ----
__global__ __launch_bounds__(256) void mfma_z(
    const half_t* __restrict__ A_sl, const half_t* __restrict__ Bp,
    half_t* __restrict__ out_sl, int n) {
    constexpr int NCT = 4;
    constexpr size_t SLAB32 = (size_t)NN * 32;
    int tid = threadIdx.x;
    int w = tid >> 6;
    int l = tid & 63;
    int c = l & 15;
    int q = l >> 4;
    int row = blockIdx.x * 64 + w * 16 + c;
    int rowc = min(row, n - 1);

    float4v acc[NCT];
#pragma unroll
    for (int i = 0; i < NCT; i++) acc[i] = (float4v){0.f, 0.f, 0.f, 0.f};

    const half_t* B = Bp + (size_t)(c * 4 + q) * 8;
#pragma unroll
    for (int ch = 0; ch < 4; ch++) {
        half8v a = load_a32(A_sl, rowc, q, ch);
        half8v b[NCT];
#pragma unroll
        for (int t2 = 0; t2 < NCT; t2++)
            b[t2] = *(const half8v*)(B + (size_t)ch * (NCT * 512) + t2 * 512);
#pragma unroll
        for (int t2 = 0; t2 < NCT; t2++)
            acc[t2] = __builtin_amdgcn_mfma_f32_16x16x32_f16(a, b[t2], acc[t2], 0, 0, 0);
    }

    int orow0 = blockIdx.x * 64 + w * 16 + q * 4;
#pragma unroll
    for (int t2 = 0; t2 < NCT; t2++) {
        int col = t2 * 16 + c;
        size_t coff = (size_t)(col >> 5) * SLAB32 + (col & 31);
#pragma unroll
        for (int r = 0; r < 4; r++) {
            int nrow = orow0 + r;
            if (nrow < n) out_sl[coff + (size_t)nrow * 32] = (half_t)acc[t2][r];
        }
    }
}

// ---- MFMA layer-3 final: out = (pz0+pz1)*invdeg + bl3 + hh@Wr3^T (fp32) ----
__global__ __launch_bounds__(256) void mfma_final(
    const half_t* __restrict__ A_sl, const half_t* __restrict__ Bp,
    const half_t* __restrict__ pz0, const half_t* __restrict__ pz1,
    const float* __restrict__ invdeg, const float* __restrict__ bias,
    float* __restrict__ out, int n) {
    constexpr int NCT = 4;
    int tid = threadIdx.x;
    int w = tid >> 6;
    int l = tid & 63;
    int c = l & 15;
    int q = l >> 4;
    int row = blockIdx.x * 64 + w * 16 + c;
    int rowc = min(row, n - 1);

    float4v acc[NCT];
#pragma unroll
    for (int i = 0; i < NCT; i++) acc[i] = (float4v){0.f, 0.f, 0.f, 0.f};

    const half_t* B = Bp + (size_t)(c * 4 + q) * 8;
#pragma unroll
    for (int ch = 0; ch < 4; ch++) {
        half8v a = load_a32(A_sl, rowc, q, ch);
        half8v b[NCT];
#pragma unroll
        for (int t2 = 0; t2 < NCT; t2++)
            b[t2] = *(const half8v*)(B + (size_t)ch * (NCT * 512) + t2 * 512);
#pragma unroll
        for (int t2 = 0; t2 < NCT; t2++)
            acc[t2] = __builtin_amdgcn_mfma_f32_16x16x32_f16(a, b[t2], acc[t2], 0, 0, 0);
    }

    int orow0 = blockIdx.x * 64 + w * 16 + q * 4;
    float ivr[4];
#pragma unroll
    for (int r = 0; r < 4; r++) {
        int nrow = orow0 + r;
        ivr[r] = (nrow < n) ? invdeg[nrow] : 0.f;
    }
#pragma unroll
    for (int t2 = 0; t2 < NCT; t2++) {
        int col = t2 * 16 + c;
        float bv = bias[col];
#pragma unroll
        for (int r = 0; r < 4; r++) {
            int nrow = orow0 + r;
            if (nrow < n) {
                float m = ((float)pz0[(size_t)nrow * 64 + col] +
                           (float)pz1[(size_t)nrow * 64 + col]) * ivr[r];
                out[(size_t)nrow * 64 + col] = acc[t2][r] + bv + m;
            }
        }
    }
}

extern "C" void kernel_launch(void* const* d_in, const int* in_sizes, int n_in,
                              void* d_out, int out_size, void* d_ws, size_t ws_size,
                              hipStream_t stream) {
    const float* x   = (const float*)d_in[0];
    const int*   ei  = (const int*)d_in[1];
    const float* Wl1 = (const float*)d_in[2];
    const float* bl1 = (const float*)d_in[3];
    const float* Wr1 = (const float*)d_in[4];
    const float* Wl2 = (const float*)d_in[5];
    const float* bl2 = (const float*)d_in[6];
    const float* Wr2 = (const float*)d_in[7];
    const float* Wl3 = (const float*)d_in[8];
    const float* bl3 = (const float*)d_in[9];
    const float* Wr3 = (const float*)d_in[10];

    const int N = NN;
    const int E = in_sizes[1] / 2;
    const int* src = ei;
    const int* dst = ei + E;

    char* ws = (char*)d_ws;
    half_t* xh_sl = (half_t*)ws;                      // [4][N][32]
    half_t* hh_sl = xh_sl + (size_t)N * 128;          // [4][N][32]
    half_t* part0 = hh_sl + (size_t)N * 128;          // [N][128]
    half_t* part1 = part0 + (size_t)N * 128;          // [N][128]
    half_t* z_grp  = xh_sl;                           // alias: [2][N][32] (xh dead by L3)
    half_t* partz0 = part0;                           // alias: [N][64]
    half_t* partz1 = part1;                           // alias: [N][64]
    int* ghist    = (int*)(part1 + (size_t)N * 128);  // 1024
    int* cptr     = ghist + 1024;                     // 1025 (pad 1028)
    int* cfill    = cptr + 1028;                      // 1024
    int* rp2      = cfill + 1024;                     // 2N+1 (pad 2N+4)
    float* invdeg = (float*)(rp2 + 2 * N + 4);        // N
    unsigned int* coarse = (unsigned int*)(invdeg + N);  // E
    int* sorted_src = (int*)(coarse + E);             // E
    half_t* Bl1 = (half_t*)(sorted_src + E);
    half_t* Br1 = Bl1 + 128 * 128;
    half_t* Bl2 = Br1 + 128 * 128;
    half_t* Br2 = Bl2 + 128 * 128;
    half_t* Bl3 = Br2 + 128 * 128;                    // 64*128
    half_t* Br3 = Bl3 + 64 * 128;

    // casts + weight prep
    cast_f2h<<<(N * 128 / 4 + 255) / 256, 256, 0, stream>>>(x, xh_sl, N * 128 / 4);
    prep_all<<<320, 256, 0, stream>>>(Wl1, Wr1, Wl2, Wr2, Wl3, Wr3,
                                      Bl1, Br1, Bl2, Br2, Bl3, Br3);

    // CSR build: two-level counting sort, fine key = (node, src_half)
    const int sort_blocks = (E + CHUNK - 1) / CHUNK;
    hipMemsetAsync(ghist, 0, 1024 * 4, stream);
    coarse_hist_kernel<<<sort_blocks, 256, 0, stream>>>(dst, ghist, E);
    coarse_scan_kernel<<<1, 1024, 0, stream>>>(ghist, cptr, cfill, rp2, N, E);
    partition_kernel<<<sort_blocks, 256, 0, stream>>>(src, dst, cfill, coarse, E);
    fine_sort_kernel<<<(N + 127) / 128, 256, 0, stream>>>(coarse, cptr, rp2, sorted_src, N);
    invdeg_kernel<<<(N + 255) / 256, 256, 0, stream>>>(rp2, invdeg, N);

    const int g128_blocks = ((N + 31) / 32) * 8;   // 25000
    const int g64_blocks  = ((N + 31) / 32) * 4;   // 12500
    const int gemm_blocks = (N + 63) / 64;

    // Layer 1: xh -> hh (relu)
    gather_part128<<<g128_blocks, 256, 0, stream>>>(xh_sl, rp2, sorted_src, part0, part1, N);
    mfma_layer128<<<gemm_blocks, 256, 0, stream>>>(xh_sl, part0, part1, invdeg,
                                                   Bl1, Br1, bl1, hh_sl, N);

    // Layer 2: hh -> hh (relu)
    gather_part128<<<g128_blocks, 256, 0, stream>>>(hh_sl, rp2, sorted_src, part0, part1, N);
    mfma_layer128<<<gemm_blocks, 256, 0, stream>>>(hh_sl, part0, part1, invdeg,
                                                   Bl2, Br2, bl2, hh_sl, N);

    // Layer 3 (transform-before-aggregate):
    //   z = hh@Wl3^T ; partial-sum gather of z ; out = mean + bl3 + hh@Wr3^T
    mfma_z<<<gemm_blocks, 256, 0, stream>>>(hh_sl, Bl3, z_grp, N);
    gather_part64<<<g64_blocks, 256, 0, stream>>>(z_grp, rp2, sorted_src, partz0, partz1, N);
    mfma_final<<<gemm_blocks, 256, 0, stream>>>(hh_sl, Br3, partz0, partz1,
                                                invdeg, bl3, (float*)d_out, N);
}

// Round 3
// 594.822 us; speedup vs baseline: 1.3654x; 1.3654x over previous
//
#include <hip/hip_runtime.h>

// GraphSAGE 3-layer: N=100000, E=3.2M, 128 -> 128 -> 128 -> 64.
// Round 9: slab gathers (R8 geometry) with TAIL-FREE padded runs.
//  - R8 post-mortem: slowdown was tail-loop serialization (half-split runs of
//    ~16 edges -> ~half of edge-visits in a rolled dependent-chain tail) plus
//    nontemporal index loads serialized at LLC latency. NOT the slab concept.
//  - Fix: fine-sort pads every (node, src-half) run to a multiple of 8 with
//    sentinel index NN -> feature tables get a zeroed row NN. Gather loops are
//    exact-count, tail-free, and hand-pipelined (next 4 indices prefetched
//    while current 4 feature loads are in flight; 8 loads/lane outstanding).
//  - Index loads are normal cached loads (nt removed); nt kept only on
//    partial-sum stores.
//  - Run bounds come from pbeg/pend arrays (bucket capacity raw+2048, so no
//    extra global scan); invdeg computed inside fine_sort (kernel dropped).
//  - Slabs: [4][N+1][32] fp16 (64B rows); slice = (chgrp, srchalf), 3.2MB
//    working set per slice, pinned to XCD by blockIdx%8.

#define NN 100000
#define CHUNK 8192

typedef _Float16 half_t;
typedef __attribute__((ext_vector_type(4))) _Float16 half4v;
typedef __attribute__((ext_vector_type(8))) _Float16 half8v;
typedef __attribute__((ext_vector_type(4))) float float4v;

// ---- Pass A: coarse histogram (LDS-privatized) ----
__global__ __launch_bounds__(256) void coarse_hist_kernel(const int* __restrict__ dst,
                                                          int* __restrict__ ghist, int E) {
    __shared__ int h[1024];
    int tid = threadIdx.x;
    for (int i = tid; i < 1024; i += 256) h[i] = 0;
    __syncthreads();
    int base = blockIdx.x * CHUNK;
    int nE = min(CHUNK, E - base);
    for (int i = tid; i < nE; i += 256) atomicAdd(&h[dst[base + i] >> 7], 1);
    __syncthreads();
    for (int i = tid; i < 1024; i += 256) {
        int v = h[i];
        if (v) atomicAdd(&ghist[i], v);
    }
}

// ---- Pass B: scan 1024 coarse bins ----
__global__ __launch_bounds__(1024) void coarse_scan_kernel(const int* __restrict__ ghist,
                                                           int* __restrict__ cptr,
                                                           int* __restrict__ cfill) {
    __shared__ int s[1024];
    int tid = threadIdx.x;
    s[tid] = ghist[tid];
    __syncthreads();
    for (int off = 1; off < 1024; off <<= 1) {
        int v = (tid >= off) ? s[tid - off] : 0;
        __syncthreads();
        s[tid] += v;
        __syncthreads();
    }
    int excl = (tid == 0) ? 0 : s[tid - 1];
    cptr[tid] = excl;
    cfill[tid] = excl;
    if (tid == 1023) cptr[1024] = s[1023];
}

// ---- Pass C: partition edges into coarse buckets (packed u32) ----
__global__ __launch_bounds__(256) void partition_kernel(const int* __restrict__ src,
                                                        const int* __restrict__ dst,
                                                        int* __restrict__ cfill,
                                                        unsigned int* __restrict__ coarse,
                                                        int E) {
    __shared__ int h[1024];
    __shared__ int off[1024];
    __shared__ int gbase[1024];
    __shared__ int ssum[256];
    __shared__ unsigned int stage[CHUNK];
    int tid = threadIdx.x;
    for (int i = tid; i < 1024; i += 256) h[i] = 0;
    __syncthreads();
    int base = blockIdx.x * CHUNK;
    int nE = min(CHUNK, E - base);
    for (int i = tid; i < nE; i += 256) atomicAdd(&h[dst[base + i] >> 7], 1);
    __syncthreads();
    int b0 = tid * 4;
    int sum = h[b0] + h[b0 + 1] + h[b0 + 2] + h[b0 + 3];
    ssum[tid] = sum;
    __syncthreads();
    for (int o = 1; o < 256; o <<= 1) {
        int v = (tid >= o) ? ssum[tid - o] : 0;
        __syncthreads();
        ssum[tid] += v;
        __syncthreads();
    }
    int run = (tid == 0) ? 0 : ssum[tid - 1];
#pragma unroll
    for (int j = 0; j < 4; j++) { off[b0 + j] = run; run += h[b0 + j]; }
    __syncthreads();
    for (int i = tid; i < nE; i += 256) {
        int d = dst[base + i];
        int s_ = src[base + i];
        int bin = d >> 7;
        int pos = atomicAdd(&off[bin], 1);
        stage[pos] = ((unsigned)(d & 127) << 17) | (unsigned)s_;
    }
    __syncthreads();
#pragma unroll
    for (int j = 0; j < 4; j++) {
        int b = b0 + j;
        if (h[b]) gbase[b] = atomicAdd(&cfill[b], h[b]);
    }
#pragma unroll
    for (int j = 0; j < 4; j++) {
        int b = b0 + j;
        int c = h[b];
        int lstart = off[b] - c;
        int gs = gbase[b];
        for (int k = 0; k < c; k++) coarse[gs + k] = stage[lstart + k];
    }
}

// ---- Pass D: fine sort by (node, src_half); pad runs to multiples of 8 ----
// Bucket b's padded region: [cptr[b] + 2048*b, ...). Padded size <= raw+1792.
// Pad entries use sentinel index NN (zeroed feature row). Writes pbeg/pend
// per (node, half) and invdeg per node.
__global__ __launch_bounds__(256) void fine_sort_kernel(const unsigned int* __restrict__ coarse,
                                                        const int* __restrict__ cptr,
                                                        int* __restrict__ pbeg,
                                                        int* __restrict__ pend,
                                                        float* __restrict__ invdeg,
                                                        int* __restrict__ sorted_src, int n) {
    __shared__ int fh[256];
    __shared__ int foff[256];
    __shared__ int cur[256];
    int b = blockIdx.x;
    int beg = cptr[b], end = cptr[b + 1];
    int nb = end - beg;
    int tid = threadIdx.x;
    fh[tid] = 0;
    __syncthreads();
    for (int i = tid; i < nb; i += 256) {
        unsigned p = coarse[beg + i];
        int f = (int)((p >> 17) << 1) | ((p & 0x1FFFF) >= (NN / 2) ? 1 : 0);
        atomicAdd(&fh[f], 1);
    }
    __syncthreads();
    int raw = fh[tid];
    int pc = (raw + 7) & ~7;
    foff[tid] = pc;
    __syncthreads();
    for (int o = 1; o < 256; o <<= 1) {
        int v = (tid >= o) ? foff[tid - o] : 0;
        __syncthreads();
        foff[tid] += v;
        __syncthreads();
    }
    int pbase = beg + b * 2048;
    int rbeg = pbase + foff[tid] - pc;
    cur[tid] = rbeg;
    int node = b * 128 + (tid >> 1);
    if (node < n) {
        pbeg[2 * node + (tid & 1)] = rbeg;
        pend[2 * node + (tid & 1)] = rbeg + pc;
    }
    __syncthreads();
    // scatter real entries
    for (int i = tid; i < nb; i += 256) {
        unsigned p = coarse[beg + i];
        int f = (int)((p >> 17) << 1) | ((p & 0x1FFFF) >= (NN / 2) ? 1 : 0);
        int pos = atomicAdd(&cur[f], 1);
        sorted_src[pos] = (int)(p & 0x1FFFF);
    }
    // pad fill (disjoint from scatter range; no sync needed)
    for (int k = raw; k < pc; k++) sorted_src[rbeg + k] = NN;
    if (tid < 128) {
        int nd = b * 128 + tid;
        if (nd < n) {
            int d = fh[2 * tid] + fh[2 * tid + 1];
            invdeg[nd] = d > 0 ? 1.0f / (float)d : 0.0f;
        }
    }
}

// ---- zero the sentinel row NN of the feature slabs ----
__global__ void zero_pad_rows(half_t* __restrict__ xh, half_t* __restrict__ hh) {
    constexpr size_t SLAB32 = (size_t)(NN + 1) * 32;
    int t = threadIdx.x;
    if (t < 256) {
        int sel = t >> 7;       // 0: xh, 1: hh
        int cg = (t >> 5) & 3;
        int c = t & 31;
        half_t* p = sel ? hh : xh;
        p[(size_t)cg * SLAB32 + (size_t)NN * 32 + c] = (half_t)0.f;
    }
}

// ---- fp32 -> fp16 cast, writes group-major [4][N+1][32] ----
__global__ void cast_f2h(const float* __restrict__ in, half_t* __restrict__ out, int n4) {
    constexpr size_t SLAB32 = (size_t)(NN + 1) * 32;
    int t = blockIdx.x * blockDim.x + threadIdx.x;
    if (t < n4) {
        float4 v = *(const float4*)(in + (size_t)t * 4);
        half4v r = {(half_t)v.x, (half_t)v.y, (half_t)v.z, (half_t)v.w};
        int e = t * 4;
        int node = e >> 7;
        int c = e & 127;
        *(half4v*)(out + (size_t)(c >> 5) * SLAB32 + (size_t)node * 32 + (c & 31)) = r;
    }
}

// ---- weight prep: fragment-contiguous fp16; all 6 weights in one launch ----
template <int C_IN, int C_OUT>
__device__ inline void prep_one(const float* __restrict__ W, half_t* __restrict__ B, int t) {
    constexpr int NCT = C_OUT / 16;
    if (t >= C_IN * C_OUT) return;
    int jj = t & 7;
    int kq = (t >> 3) & 3;
    int c = (t >> 5) & 15;
    int ct = (t >> 9) % NCT;
    int chunk = t / (512 * NCT);
    int k = chunk * 32 + kq * 8 + jj;
    int j = ct * 16 + c;
    B[t] = (half_t)W[(size_t)j * C_IN + k];
}

__global__ __launch_bounds__(256) void prep_all(
    const float* __restrict__ Wl1, const float* __restrict__ Wr1,
    const float* __restrict__ Wl2, const float* __restrict__ Wr2,
    const float* __restrict__ Wl3, const float* __restrict__ Wr3,
    half_t* Bl1, half_t* Br1, half_t* Bl2, half_t* Br2, half_t* Bl3, half_t* Br3) {
    int b = blockIdx.x;
    int tid = threadIdx.x;
    if (b < 256) {
        int sel = b >> 6;
        int t = (b & 63) * 256 + tid;
        const float* W = sel == 0 ? Wl1 : sel == 1 ? Wr1 : sel == 2 ? Wl2 : Wr2;
        half_t* B = sel == 0 ? Bl1 : sel == 1 ? Br1 : sel == 2 ? Bl2 : Br2;
        prep_one<128, 128>(W, B, t);
    } else {
        int idx = b - 256;
        int sel = idx >> 5;
        int t = (idx & 31) * 256 + tid;
        prep_one<128, 64>(sel == 0 ? Wl3 : Wr3, sel == 0 ? Bl3 : Br3, t);
    }
}

// ---- gather partial sums, 128ch: slice = (chgrp 0..3)*2 + (half 0..1) ----
// Tail-free: runs are padded to multiples of 8 (sentinel row NN = zeros).
// 8 lanes/node = 2 edge-slots x 4 col-lanes (16B each -> 64B/edge).
// Software-pipelined: next block's 4 indices prefetch under current block's
// 4 feature loads. 32 nodes/block, grid = ceil(N/32)*8.
__global__ __launch_bounds__(256) void gather_part128(
    const half_t* __restrict__ feat,   // [4][NN+1][32]
    const int* __restrict__ pbeg, const int* __restrict__ pend,
    const int* __restrict__ sorted_src,
    half_t* __restrict__ part0,        // [N][128] sums, half 0
    half_t* __restrict__ part1,        // [N][128] sums, half 1
    int n) {
    constexpr size_t SLAB32 = (size_t)(NN + 1) * 32;
    int slice = blockIdx.x & 7;
    int cg = slice >> 1;
    int s = slice & 1;
    int tid = threadIdx.x;
    int node = (blockIdx.x >> 3) * 32 + (tid >> 3);
    if (node >= n) return;
    int slot = (tid >> 2) & 1;
    int col = tid & 3;
    const half_t* base = feat + (size_t)cg * SLAB32 + col * 8;
    int beg = pbeg[2 * node + s];
    int end = pend[2 * node + s];
    float a0 = 0.f, a1 = 0.f, a2 = 0.f, a3 = 0.f, a4 = 0.f, a5 = 0.f, a6 = 0.f, a7 = 0.f;
    int j = beg + slot;
    if (j < end) {
        int s0 = sorted_src[j];
        int s1 = sorted_src[j + 2];
        int s2 = sorted_src[j + 4];
        int s3 = sorted_src[j + 6];
        for (j += 8; j < end; j += 8) {
            int t0 = sorted_src[j];
            int t1 = sorted_src[j + 2];
            int t2 = sorted_src[j + 4];
            int t3 = sorted_src[j + 6];
            half8v v0 = *(const half8v*)(base + (size_t)s0 * 32);
            half8v v1 = *(const half8v*)(base + (size_t)s1 * 32);
            half8v v2 = *(const half8v*)(base + (size_t)s2 * 32);
            half8v v3 = *(const half8v*)(base + (size_t)s3 * 32);
            a0 += ((float)v0[0] + (float)v1[0]) + ((float)v2[0] + (float)v3[0]);
            a1 += ((float)v0[1] + (float)v1[1]) + ((float)v2[1] + (float)v3[1]);
            a2 += ((float)v0[2] + (float)v1[2]) + ((float)v2[2] + (float)v3[2]);
            a3 += ((float)v0[3] + (float)v1[3]) + ((float)v2[3] + (float)v3[3]);
            a4 += ((float)v0[4] + (float)v1[4]) + ((float)v2[4] + (float)v3[4]);
            a5 += ((float)v0[5] + (float)v1[5]) + ((float)v2[5] + (float)v3[5]);
            a6 += ((float)v0[6] + (float)v1[6]) + ((float)v2[6] + (float)v3[6]);
            a7 += ((float)v0[7] + (float)v1[7]) + ((float)v2[7] + (float)v3[7]);
            s0 = t0; s1 = t1; s2 = t2; s3 = t3;
        }
        half8v v0 = *(const half8v*)(base + (size_t)s0 * 32);
        half8v v1 = *(const half8v*)(base + (size_t)s1 * 32);
        half8v v2 = *(const half8v*)(base + (size_t)s2 * 32);
        half8v v3 = *(const half8v*)(base + (size_t)s3 * 32);
        a0 += ((float)v0[0] + (float)v1[0]) + ((float)v2[0] + (float)v3[0]);
        a1 += ((float)v0[1] + (float)v1[1]) + ((float)v2[1] + (float)v3[1]);
        a2 += ((float)v0[2] + (float)v1[2]) + ((float)v2[2] + (float)v3[2]);
        a3 += ((float)v0[3] + (float)v1[3]) + ((float)v2[3] + (float)v3[3]);
        a4 += ((float)v0[4] + (float)v1[4]) + ((float)v2[4] + (float)v3[4]);
        a5 += ((float)v0[5] + (float)v1[5]) + ((float)v2[5] + (float)v3[5]);
        a6 += ((float)v0[6] + (float)v1[6]) + ((float)v2[6] + (float)v3[6]);
        a7 += ((float)v0[7] + (float)v1[7]) + ((float)v2[7] + (float)v3[7]);
    }
    // reduce across the 2 edge slots (lane bit 2)
    a0 += __shfl_xor(a0, 4); a1 += __shfl_xor(a1, 4);
    a2 += __shfl_xor(a2, 4); a3 += __shfl_xor(a3, 4);
    a4 += __shfl_xor(a4, 4); a5 += __shfl_xor(a5, 4);
    a6 += __shfl_xor(a6, 4); a7 += __shfl_xor(a7, 4);
    if (slot == 0) {
        half8v r = {(half_t)a0, (half_t)a1, (half_t)a2, (half_t)a3,
                    (half_t)a4, (half_t)a5, (half_t)a6, (half_t)a7};
        half_t* pp = (s == 0 ? part0 : part1);
        __builtin_nontemporal_store(r, (half8v*)(pp + (size_t)node * 128 + cg * 32 + col * 8));
    }
}

// ---- gather partial sums, 64ch z: slice = (chhalf 0..1)*2 + (half 0..1) ----
__global__ __launch_bounds__(256) void gather_part64(
    const half_t* __restrict__ z,      // [2][NN+1][32]
    const int* __restrict__ pbeg, const int* __restrict__ pend,
    const int* __restrict__ sorted_src,
    half_t* __restrict__ part0,        // [N][64] sums, half 0
    half_t* __restrict__ part1,        // [N][64] sums, half 1
    int n) {
    constexpr size_t SLAB32 = (size_t)(NN + 1) * 32;
    int slice = blockIdx.x & 3;
    int hg = slice >> 1;
    int s = slice & 1;
    int tid = threadIdx.x;
    int node = (blockIdx.x >> 2) * 32 + (tid >> 3);
    if (node >= n) return;
    int slot = (tid >> 2) & 1;
    int col = tid & 3;
    const half_t* base = z + (size_t)hg * SLAB32 + col * 8;
    int beg = pbeg[2 * node + s];
    int end = pend[2 * node + s];
    float a0 = 0.f, a1 = 0.f, a2 = 0.f, a3 = 0.f, a4 = 0.f, a5 = 0.f, a6 = 0.f, a7 = 0.f;
    int j = beg + slot;
    if (j < end) {
        int s0 = sorted_src[j];
        int s1 = sorted_src[j + 2];
        int s2 = sorted_src[j + 4];
        int s3 = sorted_src[j + 6];
        for (j += 8; j < end; j += 8) {
            int t0 = sorted_src[j];
            int t1 = sorted_src[j + 2];
            int t2 = sorted_src[j + 4];
            int t3 = sorted_src[j + 6];
            half8v v0 = *(const half8v*)(base + (size_t)s0 * 32);
            half8v v1 = *(const half8v*)(base + (size_t)s1 * 32);
            half8v v2 = *(const half8v*)(base + (size_t)s2 * 32);
            half8v v3 = *(const half8v*)(base + (size_t)s3 * 32);
            a0 += ((float)v0[0] + (float)v1[0]) + ((float)v2[0] + (float)v3[0]);
            a1 += ((float)v0[1] + (float)v1[1]) + ((float)v2[1] + (float)v3[1]);
            a2 += ((float)v0[2] + (float)v1[2]) + ((float)v2[2] + (float)v3[2]);
            a3 += ((float)v0[3] + (float)v1[3]) + ((float)v2[3] + (float)v3[3]);
            a4 += ((float)v0[4] + (float)v1[4]) + ((float)v2[4] + (float)v3[4]);
            a5 += ((float)v0[5] + (float)v1[5]) + ((float)v2[5] + (float)v3[5]);
            a6 += ((float)v0[6] + (float)v1[6]) + ((float)v2[6] + (float)v3[6]);
            a7 += ((float)v0[7] + (float)v1[7]) + ((float)v2[7] + (float)v3[7]);
            s0 = t0; s1 = t1; s2 = t2; s3 = t3;
        }
        half8v v0 = *(const half8v*)(base + (size_t)s0 * 32);
        half8v v1 = *(const half8v*)(base + (size_t)s1 * 32);
        half8v v2 = *(const half8v*)(base + (size_t)s2 * 32);
        half8v v3 = *(const half8v*)(base + (size_t)s3 * 32);
        a0 += ((float)v0[0] + (float)v1[0]) + ((float)v2[0] + (float)v3[0]);
        a1 += ((float)v0[1] + (float)v1[1]) + ((float)v2[1] + (float)v3[1]);
        a2 += ((float)v0[2] + (float)v1[2]) + ((float)v2[2] + (float)v3[2]);
        a3 += ((float)v0[3] + (float)v1[3]) + ((float)v2[3] + (float)v3[3]);
        a4 += ((float)v0[4] + (float)v1[4]) + ((float)v2[4] + (float)v3[4]);
        a5 += ((float)v0[5] + (float)v1[5]) + ((float)v2[5] + (float)v3[5]);
        a6 += ((float)v0[6] + (float)v1[6]) + ((float)v2[6] + (float)v3[6]);
        a7 += ((float)v0[7] + (float)v1[7]) + ((float)v2[7] + (float)v3[7]);
    }
    a0 += __shfl_xor(a0, 4); a1 += __shfl_xor(a1, 4);
    a2 += __shfl_xor(a2, 4); a3 += __shfl_xor(a3, 4);
    a4 += __shfl_xor(a4, 4); a5 += __shfl_xor(a5, 4);
    a6 += __shfl_xor(a6, 4); a7 += __shfl_xor(a7, 4);
    if (slot == 0) {
        half8v r = {(half_t)a0, (half_t)a1, (half_t)a2, (half_t)a3,
                    (half_t)a4, (half_t)a5, (half_t)a6, (half_t)a7};
        half_t* pp = (s == 0 ? part0 : part1);
        __builtin_nontemporal_store(r, (half8v*)(pp + (size_t)node * 64 + hg * 32 + col * 8));
    }
}

// ---- A-fragment load from group-major [4][N+1][32]: k = ch*32 + q*8 ----
__device__ inline half8v load_a32(const half_t* __restrict__ A, int rowc, int q, int ch) {
    constexpr size_t SLAB32 = (size_t)(NN + 1) * 32;
    return *(const half8v*)(A + (size_t)ch * SLAB32 + (size_t)rowc * 32 + q * 8);
}

// ---- MFMA layers 1,2: out = relu( ((p0+p1)*invdeg)@Wl^T + bias + root@Wr^T ) ----
__global__ __launch_bounds__(256) void mfma_layer128(
    const half_t* __restrict__ rootSl,
    const half_t* __restrict__ part0, const half_t* __restrict__ part1,
    const float* __restrict__ invdeg,
    const half_t* __restrict__ Bl, const half_t* __restrict__ Br,
    const float* __restrict__ bias, half_t* __restrict__ outSl, int n) {
    constexpr int NCT = 8;
    constexpr size_t SLAB32 = (size_t)(NN + 1) * 32;
    int tid = threadIdx.x;
    int w = tid >> 6;
    int l = tid & 63;
    int c = l & 15;
    int q = l >> 4;
    int row = blockIdx.x * 64 + w * 16 + c;
    int rowc = min(row, n - 1);
    float iv = invdeg[rowc];

    float4v acc[NCT];
#pragma unroll
    for (int i = 0; i < NCT; i++) acc[i] = (float4v){0.f, 0.f, 0.f, 0.f};

    // mean stage: a = (p0+p1)*invdeg
    {
        const half_t* B = Bl + (size_t)(c * 4 + q) * 8;
#pragma unroll
        for (int ch = 0; ch < 4; ch++) {
            half8v p0 = *(const half8v*)(part0 + (size_t)rowc * 128 + ch * 32 + q * 8);
            half8v p1 = *(const half8v*)(part1 + (size_t)rowc * 128 + ch * 32 + q * 8);
            half8v a;
#pragma unroll
            for (int i = 0; i < 8; i++) a[i] = (half_t)(((float)p0[i] + (float)p1[i]) * iv);
            half8v b[NCT];
#pragma unroll
            for (int t2 = 0; t2 < NCT; t2++)
                b[t2] = *(const half8v*)(B + (size_t)ch * (NCT * 512) + t2 * 512);
#pragma unroll
            for (int t2 = 0; t2 < NCT; t2++)
                acc[t2] = __builtin_amdgcn_mfma_f32_16x16x32_f16(a, b[t2], acc[t2], 0, 0, 0);
        }
    }
    // root stage
    {
        const half_t* B = Br + (size_t)(c * 4 + q) * 8;
#pragma unroll
        for (int ch = 0; ch < 4; ch++) {
            half8v a = load_a32(rootSl, rowc, q, ch);
            half8v b[NCT];
#pragma unroll
            for (int t2 = 0; t2 < NCT; t2++)
                b[t2] = *(const half8v*)(B + (size_t)ch * (NCT * 512) + t2 * 512);
#pragma unroll
            for (int t2 = 0; t2 < NCT; t2++)
                acc[t2] = __builtin_amdgcn_mfma_f32_16x16x32_f16(a, b[t2], acc[t2], 0, 0, 0);
        }
    }

    int orow0 = blockIdx.x * 64 + w * 16 + q * 4;
#pragma unroll
    for (int t2 = 0; t2 < NCT; t2++) {
        int col = t2 * 16 + c;
        float bv = bias[col];
        size_t coff = (size_t)(col >> 5) * SLAB32 + (col & 31);
#pragma unroll
        for (int r = 0; r < 4; r++) {
            int nrow = orow0 + r;
            if (nrow < n)
                outSl[coff + (size_t)nrow * 32] = (half_t)fmaxf(acc[t2][r] + bv, 0.f);
        }
    }
}

// ---- MFMA layer-3 pre-transform: z = hh@Wl3^T, out group-major [2][N+1][32] ----
__global__ __launch_bounds__(256) void mfma_z(
    const half_t* __restrict__ A_sl, const half_t* __restrict__ Bp,
    half_t* __restrict__ out_sl, int n) {
    constexpr int NCT = 4;
    constexpr size_t SLAB32 = (size_t)(NN + 1) * 32;
    int tid = threadIdx.x;
    int w = tid >> 6;
    int l = tid & 63;
    int c = l & 15;
    int q = l >> 4;
    int row = blockIdx.x * 64 + w * 16 + c;
    int rowc = min(row, n - 1);

    float4v acc[NCT];
#pragma unroll
    for (int i = 0; i < NCT; i++) acc[i] = (float4v){0.f, 0.f, 0.f, 0.f};

    const half_t* B = Bp + (size_t)(c * 4 + q) * 8;
#pragma unroll
    for (int ch = 0; ch < 4; ch++) {
        half8v a = load_a32(A_sl, rowc, q, ch);
        half8v b[NCT];
#pragma unroll
        for (int t2 = 0; t2 < NCT; t2++)
            b[t2] = *(const half8v*)(B + (size_t)ch * (NCT * 512) + t2 * 512);
#pragma unroll
        for (int t2 = 0; t2 < NCT; t2++)
            acc[t2] = __builtin_amdgcn_mfma_f32_16x16x32_f16(a, b[t2], acc[t2], 0, 0, 0);
    }

    int orow0 = blockIdx.x * 64 + w * 16 + q * 4;
#pragma unroll
    for (int t2 = 0; t2 < NCT; t2++) {
        int col = t2 * 16 + c;
        size_t coff = (size_t)(col >> 5) * SLAB32 + (col & 31);
#pragma unroll
        for (int r = 0; r < 4; r++) {
            int nrow = orow0 + r;
            if (nrow < n) out_sl[coff + (size_t)nrow * 32] = (half_t)acc[t2][r];
        }
    }
}

// ---- MFMA layer-3 final: out = (pz0+pz1)*invdeg + bl3 + hh@Wr3^T (fp32) ----
__global__ __launch_bounds__(256) void mfma_final(
    const half_t* __restrict__ A_sl, const half_t* __restrict__ Bp,
    const half_t* __restrict__ pz0, const half_t* __restrict__ pz1,
    const float* __restrict__ invdeg, const float* __restrict__ bias,
    float* __restrict__ out, int n) {
    constexpr int NCT = 4;
    int tid = threadIdx.x;
    int w = tid >> 6;
    int l = tid & 63;
    int c = l & 15;
    int q = l >> 4;
    int row = blockIdx.x * 64 + w * 16 + c;
    int rowc = min(row, n - 1);

    float4v acc[NCT];
#pragma unroll
    for (int i = 0; i < NCT; i++) acc[i] = (float4v){0.f, 0.f, 0.f, 0.f};

    const half_t* B = Bp + (size_t)(c * 4 + q) * 8;
#pragma unroll
    for (int ch = 0; ch < 4; ch++) {
        half8v a = load_a32(A_sl, rowc, q, ch);
        half8v b[NCT];
#pragma unroll
        for (int t2 = 0; t2 < NCT; t2++)
            b[t2] = *(const half8v*)(B + (size_t)ch * (NCT * 512) + t2 * 512);
#pragma unroll
        for (int t2 = 0; t2 < NCT; t2++)
            acc[t2] = __builtin_amdgcn_mfma_f32_16x16x32_f16(a, b[t2], acc[t2], 0, 0, 0);
    }

    int orow0 = blockIdx.x * 64 + w * 16 + q * 4;
    float ivr[4];
#pragma unroll
    for (int r = 0; r < 4; r++) {
        int nrow = orow0 + r;
        ivr[r] = (nrow < n) ? invdeg[nrow] : 0.f;
    }
#pragma unroll
    for (int t2 = 0; t2 < NCT; t2++) {
        int col = t2 * 16 + c;
        float bv = bias[col];
#pragma unroll
        for (int r = 0; r < 4; r++) {
            int nrow = orow0 + r;
            if (nrow < n) {
                float m = ((float)pz0[(size_t)nrow * 64 + col] +
                           (float)pz1[(size_t)nrow * 64 + col]) * ivr[r];
                out[(size_t)nrow * 64 + col] = acc[t2][r] + bv + m;
            }
        }
    }
}

extern "C" void kernel_launch(void* const* d_in, const int* in_sizes, int n_in,
                              void* d_out, int out_size, void* d_ws, size_t ws_size,
                              hipStream_t stream) {
    const float* x   = (const float*)d_in[0];
    const int*   ei  = (const int*)d_in[1];
    const float* Wl1 = (const float*)d_in[2];
    const float* bl1 = (const float*)d_in[3];
    const float* Wr1 = (const float*)d_in[4];
    const float* Wl2 = (const float*)d_in[5];
    const float* bl2 = (const float*)d_in[6];
    const float* Wr2 = (const float*)d_in[7];
    const float* Wl3 = (const float*)d_in[8];
    const float* bl3 = (const float*)d_in[9];
    const float* Wr3 = (const float*)d_in[10];

    const int N = NN;
    const int E = in_sizes[1] / 2;
    const int* src = ei;
    const int* dst = ei + E;

    const size_t SLABSZ = (size_t)(NN + 1) * 32;   // halfs per channel-group slab

    char* ws = (char*)d_ws;
    half_t* xh_sl = (half_t*)ws;                      // [4][N+1][32]
    half_t* hh_sl = xh_sl + 4 * SLABSZ;               // [4][N+1][32]
    half_t* part0 = hh_sl + 4 * SLABSZ;               // [N][128]
    half_t* part1 = part0 + (size_t)N * 128;          // [N][128]
    half_t* z_grp  = xh_sl;                           // alias: [2][N+1][32] (xh dead by L3)
    half_t* partz0 = part0;                           // alias: [N][64]
    half_t* partz1 = part1;                           // alias: [N][64]
    int* ghist    = (int*)(part1 + (size_t)N * 128);  // 1024
    int* cptr     = ghist + 1024;                     // 1025 (pad 1028)
    int* cfill    = cptr + 1028;                      // 1024
    int* pbeg     = cfill + 1024;                     // 2N (+256 pad)
    int* pend     = pbeg + 2 * N + 256;               // 2N (+256 pad)
    float* invdeg = (float*)(pend + 2 * N + 256);     // N
    unsigned int* coarse = (unsigned int*)(invdeg + N);  // E
    int* sorted_src = (int*)(coarse + E);             // E + 1024*2048 + 64
    half_t* Bl1 = (half_t*)(sorted_src + E + 1024 * 2048 + 64);
    half_t* Br1 = Bl1 + 128 * 128;
    half_t* Bl2 = Br1 + 128 * 128;
    half_t* Br2 = Bl2 + 128 * 128;
    half_t* Bl3 = Br2 + 128 * 128;                    // 64*128
    half_t* Br3 = Bl3 + 64 * 128;

    // casts + weight prep + sentinel rows
    cast_f2h<<<(N * 128 / 4 + 255) / 256, 256, 0, stream>>>(x, xh_sl, N * 128 / 4);
    prep_all<<<320, 256, 0, stream>>>(Wl1, Wr1, Wl2, Wr2, Wl3, Wr3,
                                      Bl1, Br1, Bl2, Br2, Bl3, Br3);
    zero_pad_rows<<<1, 256, 0, stream>>>(xh_sl, hh_sl);

    // CSR build: two-level counting sort, fine key = (node, src_half), padded
    const int sort_blocks = (E + CHUNK - 1) / CHUNK;
    hipMemsetAsync(ghist, 0, 1024 * 4, stream);
    coarse_hist_kernel<<<sort_blocks, 256, 0, stream>>>(dst, ghist, E);
    coarse_scan_kernel<<<1, 1024, 0, stream>>>(ghist, cptr, cfill);
    partition_kernel<<<sort_blocks, 256, 0, stream>>>(src, dst, cfill, coarse, E);
    fine_sort_kernel<<<(N + 127) / 128, 256, 0, stream>>>(coarse, cptr, pbeg, pend,
                                                          invdeg, sorted_src, N);

    const int g128_blocks = ((N + 31) / 32) * 8;   // 25000
    const int g64_blocks  = ((N + 31) / 32) * 4;   // 12500
    const int gemm_blocks = (N + 63) / 64;

    // Layer 1: xh -> hh (relu)
    gather_part128<<<g128_blocks, 256, 0, stream>>>(xh_sl, pbeg, pend, sorted_src,
                                                    part0, part1, N);
    mfma_layer128<<<gemm_blocks, 256, 0, stream>>>(xh_sl, part0, part1, invdeg,
                                                   Bl1, Br1, bl1, hh_sl, N);

    // Layer 2: hh -> hh (relu)
    gather_part128<<<g128_blocks, 256, 0, stream>>>(hh_sl, pbeg, pend, sorted_src,
                                                    part0, part1, N);
    mfma_layer128<<<gemm_blocks, 256, 0, stream>>>(hh_sl, part0, part1, invdeg,
                                                   Bl2, Br2, bl2, hh_sl, N);

    // Layer 3 (transform-before-aggregate):
    //   z = hh@Wl3^T ; partial-sum gather of z ; out = mean + bl3 + hh@Wr3^T
    mfma_z<<<gemm_blocks, 256, 0, stream>>>(hh_sl, Bl3, z_grp, N);
    gather_part64<<<g64_blocks, 256, 0, stream>>>(z_grp, pbeg, pend, sorted_src,
                                                  partz0, partz1, N);
    mfma_final<<<gemm_blocks, 256, 0, stream>>>(hh_sl, Br3, partz0, partz1,
                                                invdeg, bl3, (float*)d_out, N);
}